// Round 10
// baseline (10632.995 us; speedup 1.0000x reference)
//
#include <hip/hip_runtime.h>
#include <hip/hip_bf16.h>
#include <math.h>

typedef __hip_bfloat16 bf16;

static constexpr int NB = 8, TT = 10, HH = 16, WW = 16, CC = 512;
static constexpr int NHEAD = 8, HIDN = 2048;
static constexpr int MTOK = NB * TT * HH * WW;          // 20480 tokens
static constexpr size_t MC = (size_t)MTOK * CC;         // 10485760
static constexpr float LNEPS = 1e-5f;
static constexpr float ATTSCALE = 0.125f;               // 1/sqrt(64)

static __device__ __forceinline__ float gelu_f(float x) {
    return 0.5f * x * (1.0f + erff(x * 0.70710678118654752f));
}

// ---------------- ws-too-small diagnostic (fp32 fill) ----------------
__global__ __launch_bounds__(256) void k_fill(float* __restrict__ out, float v, size_t n)
{
    size_t i = (size_t)blockIdx.x * 256 + threadIdx.x;
    if (i < n) out[i] = v;
}

// ---------------- fused LayerNorm (+permute, +pos); X fp32, dst bf16 ----------------
// mode 0: dstA[m]=ln ; mode 1: win ; mode 3: temporal ; mode 4: ts
__global__ __launch_bounds__(64) void k_ln2(const float* __restrict__ X, bf16* __restrict__ dstA,
                                            bf16* __restrict__ dstB,
                                            const float* __restrict__ g, const float* __restrict__ b,
                                            const float* __restrict__ pos, int posoff, int mode)
{
    int m = blockIdx.x;
    int lane = threadIdx.x;
    const float* row = X + (size_t)m * CC;
    float v[8], s = 0.f, s2 = 0.f;
#pragma unroll
    for (int i = 0; i < 8; ++i) { v[i] = row[lane + i * 64]; s += v[i]; s2 += v[i] * v[i]; }
#pragma unroll
    for (int msk = 1; msk < 64; msk <<= 1) { s += __shfl_xor(s, msk); s2 += __shfl_xor(s2, msk); }
    float mean = s * (1.f / 512.f);
    float var  = fmaxf(s2 * (1.f / 512.f) - mean * mean, 0.f);
    float rr = rsqrtf(var + LNEPS);

    int r, pr = 0;
    if (mode == 0) { r = m; }
    else if (mode == 1) {
        int nt = m >> 8, hw = m & 255, h = hw >> 4, w = hw & 15;
        int l = (h & 7) * 8 + (w & 7);
        r = l * 320 + nt * 4 + (h >> 3) * 2 + (w >> 3);
        pr = l;
    } else if (mode == 3) {
        int n = m / 2560, rem = m - n * 2560;
        int t = rem >> 8;
        r = t * 2048 + n * 256 + (rem & 255);
        pr = t;
    } else {
        int n = m / 2560, rem = m - n * 2560;
        int t = rem >> 8, hw = rem & 255, h = hw >> 4, w = hw & 15;
        int ij = (h & 7) * 8 + (w & 7);
        r = (t * 64 + ij) * 32 + n * 4 + (h >> 3) * 2 + (w >> 3);
        pr = t * 64 + ij;
    }
#pragma unroll
    for (int i = 0; i < 8; ++i) {
        int c = lane + i * 64;
        float y = (v[i] - mean) * rr * g[c] + b[c];
        if (dstA) dstA[(size_t)r * CC + c] = __float2bfloat16(y);
        if (dstB) dstB[(size_t)r * CC + c] = __float2bfloat16(y + pos[(size_t)(posoff + pr) * CC + c]);
    }
}

// ---------------- gather-permute of fp32 `memory` into ts layout (+optional pos) ----------------
__global__ __launch_bounds__(256) void k_permmem(const float* __restrict__ in, bf16* __restrict__ out,
                                                 const float* __restrict__ pos, int posoff)
{
    size_t id = (size_t)blockIdx.x * 256 + threadIdx.x;
    if (id >= MC) return;
    int c = (int)(id & 511);
    int r = (int)(id >> 9);
    int b = r & 31, s = r >> 5;
    int t = s >> 6, ij = s & 63;
    int i = ij >> 3, j = ij & 7;
    int n = b >> 2, qh = (b >> 1) & 1, qw = b & 1;
    int m = (n * 10 + t) * 256 + (qh * 8 + i) * 16 + qw * 8 + j;
    float v = in[(size_t)m * CC + c];
    if (pos) v += pos[(size_t)(posoff + t * 64 + ij) * CC + c];
    out[id] = __float2bfloat16(v);
}

// ---------------- reverse permute + residual add into fp32 X ----------------
__global__ __launch_bounds__(256) void k_unperm_add(float* __restrict__ X, const bf16* __restrict__ Tb, int mode)
{
    size_t id = (size_t)blockIdx.x * 256 + threadIdx.x;
    if (id >= MC) return;
    int c = (int)(id & 511);
    int m = (int)(id >> 9);
    int r;
    if (mode == 1) {
        int nt = m >> 8, hw = m & 255;
        int h = hw >> 4, w = hw & 15;
        r = ((h & 7) * 8 + (w & 7)) * 320 + nt * 4 + (h >> 3) * 2 + (w >> 3);
    } else if (mode == 3) {
        int n = m / 2560, rem = m - n * 2560;
        r = (rem >> 8) * 2048 + n * 256 + (rem & 255);
    } else {
        int n = m / 2560, rem = m - n * 2560;
        int t = rem >> 8, hw = rem & 255;
        int h = hw >> 4, w = hw & 15;
        r = (t * 64 + (h & 7) * 8 + (w & 7)) * 32 + n * 4 + (h >> 3) * 2 + (w >> 3);
    }
    X[id] += (float)Tb[(size_t)r * CC + c];
}

__global__ __launch_bounds__(256) void k_add(float* __restrict__ X, const bf16* __restrict__ Y, size_t n)
{
    size_t i = (size_t)blockIdx.x * 256 + threadIdx.x;
    if (i < n) X[i] += (float)Y[i];
}

// ---------------- final residual add: FLOAT32 output ----------------
__global__ __launch_bounds__(256) void k_final(const float* __restrict__ X, const bf16* __restrict__ F,
                                               float* __restrict__ out, size_t n)
{
    size_t i = (size_t)blockIdx.x * 256 + threadIdx.x;
    if (i < n) out[i] = X[i] + (float)F[i];
}

// ---------------- generic GEMM: C = A(bf16) @ W(fp32,Nc x K)^T + bias; out bf16 ----------------
// EPI 0: bias.  1: bias+BN+GELU.  3: bias+GELU.
template<int EPI>
__global__ __launch_bounds__(256) void k_gemm(const bf16* __restrict__ A, const float* __restrict__ Wt,
                                              const float* __restrict__ bias, bf16* __restrict__ Cout,
                                              int Nc, int K,
                                              const float* __restrict__ bng, const float* __restrict__ bnb,
                                              const float* __restrict__ bnm, const float* __restrict__ bnv)
{
    __shared__ float As[16][68];
    __shared__ float Bs[16][68];
    int bm = blockIdx.y * 64, bn = blockIdx.x * 64;
    int tid = threadIdx.x;
    int ty = tid >> 4, tx = tid & 15;
    float acc[4][4] = {};
    for (int k0 = 0; k0 < K; k0 += 16) {
#pragma unroll
        for (int t = 0; t < 4; ++t) {
            int e = tid + t * 256;
            int m = e >> 4, kk = e & 15;
            As[kk][m] = (float)A[(size_t)(bm + m) * K + k0 + kk];
            Bs[kk][m] = Wt[(size_t)(bn + m) * K + k0 + kk];
        }
        __syncthreads();
#pragma unroll
        for (int kk = 0; kk < 16; ++kk) {
            const float4 av = *reinterpret_cast<const float4*>(&As[kk][ty * 4]);
            const float4 bv = *reinterpret_cast<const float4*>(&Bs[kk][tx * 4]);
            float a[4] = {av.x, av.y, av.z, av.w};
            float b[4] = {bv.x, bv.y, bv.z, bv.w};
#pragma unroll
            for (int i = 0; i < 4; ++i)
#pragma unroll
                for (int j = 0; j < 4; ++j) acc[i][j] += a[i] * b[j];
        }
        __syncthreads();
    }
#pragma unroll
    for (int i = 0; i < 4; ++i) {
        int m = bm + ty * 4 + i;
#pragma unroll
        for (int j = 0; j < 4; ++j) {
            int n = bn + tx * 4 + j;
            float v = acc[i][j] + bias[n];
            if constexpr (EPI == 1) {
                v = (v - bnm[n]) * rsqrtf(bnv[n] + LNEPS) * bng[n] + bnb[n];
                v = gelu_f(v);
            }
            if constexpr (EPI == 3) v = gelu_f(v);
            Cout[(size_t)m * Nc + n] = __float2bfloat16(v);
        }
    }
}

// ---------------- fused fc2 GEMM over a 4096-token chunk ----------------
__global__ __launch_bounds__(256) void k_gemm_dw(const bf16* __restrict__ H1c, const float* __restrict__ Wt,
                                                 const float* __restrict__ bias, bf16* __restrict__ Cout,
                                                 int tokoff,
                                                 const float* __restrict__ dww, const float* __restrict__ dwb,
                                                 const float* __restrict__ g2, const float* __restrict__ b2,
                                                 const float* __restrict__ m2, const float* __restrict__ v2,
                                                 const float* __restrict__ g3, const float* __restrict__ b3,
                                                 const float* __restrict__ m3, const float* __restrict__ v3)
{
    __shared__ float As[16][68];
    __shared__ float Bs[16][68];
    int bm = blockIdx.y * 64, bn = blockIdx.x * 64;
    int tid = threadIdx.x;
    int ty = tid >> 4, tx = tid & 15;
    float acc[4][4] = {};
    for (int k0 = 0; k0 < HIDN; k0 += 16) {
#pragma unroll
        for (int t = 0; t < 4; ++t) {
            int e = tid + t * 256;
            int mm = e >> 4, kk = e & 15;
            int lm = bm + mm;
            int k = k0 + kk;
            int p = lm >> 8, hw = lm & 255, h = hw >> 4, w = hw & 15;
            float a = dwb[k];
#pragma unroll
            for (int dh = -1; dh <= 1; ++dh) {
                int h2 = h + dh;
                if (h2 < 0 || h2 > 15) continue;
#pragma unroll
                for (int dw = -1; dw <= 1; ++dw) {
                    int w2 = w + dw;
                    if (w2 < 0 || w2 > 15) continue;
                    a += (float)H1c[(((size_t)p * 16 + h2) * 16 + w2) * HIDN + k]
                       * dww[k * 9 + (dh + 1) * 3 + (dw + 1)];
                }
            }
            float xn = (a - m2[k]) * rsqrtf(v2[k] + LNEPS) * g2[k] + b2[k];
            As[kk][mm] = gelu_f(xn);
            Bs[kk][mm] = Wt[(size_t)(bn + mm) * HIDN + k];
        }
        __syncthreads();
#pragma unroll
        for (int kk = 0; kk < 16; ++kk) {
            const float4 av = *reinterpret_cast<const float4*>(&As[kk][ty * 4]);
            const float4 bv = *reinterpret_cast<const float4*>(&Bs[kk][tx * 4]);
            float a[4] = {av.x, av.y, av.z, av.w};
            float b[4] = {bv.x, bv.y, bv.z, bv.w};
#pragma unroll
            for (int i = 0; i < 4; ++i)
#pragma unroll
                for (int j = 0; j < 4; ++j) acc[i][j] += a[i] * b[j];
        }
        __syncthreads();
    }
#pragma unroll
    for (int i = 0; i < 4; ++i) {
        int m = tokoff + bm + ty * 4 + i;
#pragma unroll
        for (int j = 0; j < 4; ++j) {
            int n = bn + tx * 4 + j;
            float v = acc[i][j] + bias[n];
            v = (v - m3[n]) * rsqrtf(v3[n] + LNEPS) * g3[n] + b3[n];
            v = gelu_f(v);
            Cout[(size_t)m * CC + n] = __float2bfloat16(v);
        }
    }
}

// ---------------- generic MHA core: rows r = l*Bc + b, d=64, NH=8; bf16 I/O ----------------
__global__ __launch_bounds__(256) void k_attn(const bf16* __restrict__ Q, const bf16* __restrict__ K,
                                              const bf16* __restrict__ V, bf16* __restrict__ O,
                                              int L, int S, int Bc)
{
    __shared__ float sQ[16][68];
    __shared__ float sK[32][68];
    __shared__ float sV[32][68];
    __shared__ float sS[16][640];
    __shared__ float sRed[16][17];
    int b = blockIdx.x / NHEAD;
    int h = blockIdx.x - b * NHEAD;
    int ql0 = blockIdx.y * 16;
    int tid = threadIdx.x;
    int qi = tid >> 4, g = tid & 15;
    int SCv = (S + 31) & ~31;

    for (int t = tid; t < 16 * 64; t += 256) {
        int r = t >> 6, d = t & 63;
        int l = ql0 + r;
        sQ[r][d] = (l < L) ? (float)Q[((size_t)l * Bc + b) * CC + h * 64 + d] : 0.f;
    }
    __syncthreads();

    for (int s0 = 0; s0 < S; s0 += 32) {
        for (int t = tid; t < 32 * 64; t += 256) {
            int r = t >> 6, d = t & 63;
            int s = s0 + r;
            sK[r][d] = (s < S) ? (float)K[((size_t)s * Bc + b) * CC + h * 64 + d] : 0.f;
        }
        __syncthreads();
#pragma unroll
        for (int half = 0; half < 2; ++half) {
            int si = half * 16 + g;
            int s = s0 + si;
            float acc = 0.f;
#pragma unroll
            for (int d = 0; d < 64; ++d) acc += sQ[qi][d] * sK[si][d];
            sS[qi][s] = (s < S) ? acc * ATTSCALE : -60.f;
        }
        __syncthreads();
    }

    float pm = -60.f;
    for (int s = g; s < SCv; s += 16) pm = fmaxf(pm, sS[qi][s]);
    sRed[qi][g] = pm;
    __syncthreads();
    float mx = sRed[qi][0];
#pragma unroll
    for (int t = 1; t < 16; ++t) mx = fmaxf(mx, sRed[qi][t]);
    __syncthreads();
    float ps = 0.f;
    for (int s = g; s < SCv; s += 16) {
        float e = expf(sS[qi][s] - mx);
        sS[qi][s] = e;
        ps += e;
    }
    sRed[qi][g] = ps;
    __syncthreads();
    float sum = 0.f;
#pragma unroll
    for (int t = 0; t < 16; ++t) sum += sRed[qi][t];
    float inv = 1.f / fmaxf(sum, 1e-20f);

    float o0 = 0.f, o1 = 0.f, o2 = 0.f, o3 = 0.f;
    for (int s0 = 0; s0 < S; s0 += 32) {
        __syncthreads();
        for (int t = tid; t < 32 * 64; t += 256) {
            int r = t >> 6, d = t & 63;
            int s = s0 + r;
            sV[r][d] = (s < S) ? (float)V[((size_t)s * Bc + b) * CC + h * 64 + d] : 0.f;
        }
        __syncthreads();
#pragma unroll
        for (int si = 0; si < 32; ++si) {
            float w = sS[qi][s0 + si];
            o0 += w * sV[si][g * 4 + 0];
            o1 += w * sV[si][g * 4 + 1];
            o2 += w * sV[si][g * 4 + 2];
            o3 += w * sV[si][g * 4 + 3];
        }
    }
    int l = ql0 + qi;
    if (l < L) {
        bf16* op = O + ((size_t)l * Bc + b) * CC + h * 64 + g * 4;
        op[0] = __float2bfloat16(o0 * inv);
        op[1] = __float2bfloat16(o1 * inv);
        op[2] = __float2bfloat16(o2 * inv);
        op[3] = __float2bfloat16(o3 * inv);
    }
}

extern "C" void kernel_launch(void* const* d_in, const int* in_sizes, int n_in,
                              void* d_out, int out_size, void* d_ws, size_t ws_size,
                              hipStream_t stream)
{
    // All inputs float32 (reference setup_inputs uses jnp.float32). Output float32.
    const float* query        = (const float*)d_in[0];
    const float* memory       = (const float*)d_in[1];
    const float* pos_local    = (const float*)d_in[2];
    const float* pos_temporal = (const float*)d_in[3];
    const float* pos_ts       = (const float*)d_in[4];
    const float* ln_g[5] = {(const float*)d_in[5], (const float*)d_in[7], (const float*)d_in[9], (const float*)d_in[11], (const float*)d_in[13]};
    const float* ln_b[5] = {(const float*)d_in[6], (const float*)d_in[8], (const float*)d_in[10], (const float*)d_in[12], (const float*)d_in[14]};
    const float* sa_w_in  = (const float*)d_in[15]; const float* sa_b_in  = (const float*)d_in[16];
    const float* sa_w_out = (const float*)d_in[17]; const float* sa_b_out = (const float*)d_in[18];
    const float* ta_w_in  = (const float*)d_in[19]; const float* ta_b_in  = (const float*)d_in[20];
    const float* ta_w_out = (const float*)d_in[21]; const float* ta_b_out = (const float*)d_in[22];
    const float* ca_w_in  = (const float*)d_in[23]; const float* ca_b_in  = (const float*)d_in[24];
    const float* ca_w_out = (const float*)d_in[25]; const float* ca_b_out = (const float*)d_in[26];
    const float* fc1_w = (const float*)d_in[27]; const float* fc1_b = (const float*)d_in[28];
    const float* dw_w  = (const float*)d_in[29]; const float* dw_b  = (const float*)d_in[30];
    const float* fc2_w = (const float*)d_in[31]; const float* fc2_b = (const float*)d_in[32];
    const float* bn1g = (const float*)d_in[33], *bn1b = (const float*)d_in[34], *bn1m = (const float*)d_in[35], *bn1v = (const float*)d_in[36];
    const float* bn2g = (const float*)d_in[37], *bn2b = (const float*)d_in[38], *bn2m = (const float*)d_in[39], *bn2v = (const float*)d_in[40];
    const float* bn3g = (const float*)d_in[41], *bn3b = (const float*)d_in[42], *bn3m = (const float*)d_in[43], *bn3v = (const float*)d_in[44];
    const float* lin1_w = (const float*)d_in[45]; const float* lin1_b = (const float*)d_in[46];
    const float* lin2_w = (const float*)d_in[47]; const float* lin2_b = (const float*)d_in[48];

    dim3 blk(256);
    int gMC = (int)(MC / 256);

    size_t need = MC * 4 + 4 * MC * 2;
    if (ws_size < need) {
        k_fill<<<gMC, blk, 0, stream>>>((float*)d_out, 700.f, MC);
        return;
    }
    float* X = (float*)d_ws;
    bf16* B0 = (bf16*)((char*)d_ws + MC * 4);
    bf16* B1 = B0 + MC;
    bf16* B2 = B1 + MC;
    bf16* B3 = B2 + MC;
    const float* nulf = nullptr;
    bf16* nulm = nullptr;

    hipMemcpyAsync(X, query, MC * sizeof(float), hipMemcpyDeviceToDevice, stream);

    // ---- stage 1: spatial window MHSA ----
    k_ln2<<<MTOK, 64, 0, stream>>>(X, B0, B1, ln_g[0], ln_b[0], pos_local, 0, 1);
    k_gemm<0><<<dim3(8, 320), blk, 0, stream>>>(B1, sa_w_in, sa_b_in, B2, 512, 512, nulf, nulf, nulf, nulf);
    k_gemm<0><<<dim3(8, 320), blk, 0, stream>>>(B1, sa_w_in + 512 * 512, sa_b_in + 512, B3, 512, 512, nulf, nulf, nulf, nulf);
    k_gemm<0><<<dim3(8, 320), blk, 0, stream>>>(B0, sa_w_in + 2 * 512 * 512, sa_b_in + 1024, B1, 512, 512, nulf, nulf, nulf, nulf);
    k_attn<<<dim3(320 * NHEAD, 4), blk, 0, stream>>>(B2, B3, B1, B0, 64, 64, 320);
    k_gemm<0><<<dim3(8, 320), blk, 0, stream>>>(B0, sa_w_out, sa_b_out, B2, 512, 512, nulf, nulf, nulf, nulf);
    k_unperm_add<<<gMC, blk, 0, stream>>>(X, B2, 1);

    // ---- stage 2: MlpDWBN, chunked over 16-plane slabs ----
    k_ln2<<<MTOK, 64, 0, stream>>>(X, B0, nulm, ln_g[1], ln_b[1], nulf, 0, 0);
    for (int c = 0; c < 5; ++c) {
        int off = c * 4096;
        k_gemm<1><<<dim3(32, 64), blk, 0, stream>>>(B0 + (size_t)off * CC, fc1_w, fc1_b, B1, 2048, 512,
                                                    bn1g, bn1b, bn1m, bn1v);
        k_gemm_dw<<<dim3(8, 64), blk, 0, stream>>>(B1, fc2_w, fc2_b, B2, off, dw_w, dw_b,
                                                   bn2g, bn2b, bn2m, bn2v, bn3g, bn3b, bn3m, bn3v);
    }
    k_add<<<gMC, blk, 0, stream>>>(X, B2, MC);

    // ---- stage 3: temporal MHSA ----
    k_ln2<<<MTOK, 64, 0, stream>>>(X, B0, B1, ln_g[2], ln_b[2], pos_temporal, 0, 3);
    k_gemm<0><<<dim3(8, 320), blk, 0, stream>>>(B1, ta_w_in, ta_b_in, B2, 512, 512, nulf, nulf, nulf, nulf);
    k_gemm<0><<<dim3(8, 320), blk, 0, stream>>>(B1, ta_w_in + 512 * 512, ta_b_in + 512, B3, 512, 512, nulf, nulf, nulf, nulf);
    k_gemm<0><<<dim3(8, 320), blk, 0, stream>>>(B0, ta_w_in + 2 * 512 * 512, ta_b_in + 1024, B1, 512, 512, nulf, nulf, nulf, nulf);
    k_attn<<<dim3(2048 * NHEAD, 1), blk, 0, stream>>>(B2, B3, B1, B0, 10, 10, 2048);
    k_gemm<0><<<dim3(8, 320), blk, 0, stream>>>(B0, ta_w_out, ta_b_out, B2, 512, 512, nulf, nulf, nulf, nulf);
    k_unperm_add<<<gMC, blk, 0, stream>>>(X, B2, 3);

    // ---- stage 4: temporal-spatial cross-attention ----
    k_ln2<<<MTOK, 64, 0, stream>>>(X, nulm, B1, ln_g[3], ln_b[3], pos_ts, 640, 4);
    k_gemm<0><<<dim3(8, 320), blk, 0, stream>>>(B1, ca_w_in, ca_b_in, B2, 512, 512, nulf, nulf, nulf, nulf);
    k_permmem<<<gMC, blk, 0, stream>>>(memory, B1, pos_ts, 0);
    k_gemm<0><<<dim3(8, 320), blk, 0, stream>>>(B1, ca_w_in + 512 * 512, ca_b_in + 512, B3, 512, 512, nulf, nulf, nulf, nulf);
    k_permmem<<<gMC, blk, 0, stream>>>(memory, B1, nulf, 0);
    k_gemm<0><<<dim3(8, 320), blk, 0, stream>>>(B1, ca_w_in + 2 * 512 * 512, ca_b_in + 1024, B0, 512, 512, nulf, nulf, nulf, nulf);
    k_attn<<<dim3(32 * NHEAD, 40), blk, 0, stream>>>(B2, B3, B0, B1, 640, 640, 32);
    k_gemm<0><<<dim3(8, 320), blk, 0, stream>>>(B1, ca_w_out, ca_b_out, B2, 512, 512, nulf, nulf, nulf, nulf);
    k_unperm_add<<<gMC, blk, 0, stream>>>(X, B2, 4);

    // ---- stage 5: final FFN, chunked ----
    k_ln2<<<MTOK, 64, 0, stream>>>(X, B0, nulm, ln_g[4], ln_b[4], nulf, 0, 0);
    for (int c = 0; c < 5; ++c) {
        int off = c * 4096;
        k_gemm<3><<<dim3(32, 64), blk, 0, stream>>>(B0 + (size_t)off * CC, lin1_w, lin1_b, B1, 2048, 512,
                                                    nulf, nulf, nulf, nulf);
        k_gemm<0><<<dim3(8, 64), blk, 0, stream>>>(B1, lin2_w, lin2_b, B2 + (size_t)off * CC, 512, 2048,
                                                   nulf, nulf, nulf, nulf);
    }
    k_final<<<gMC, blk, 0, stream>>>(X, B2, (float*)d_out, MC);
}

// Round 11
// 5342.870 us; speedup vs baseline: 1.9901x; 1.9901x over previous
//
#include <hip/hip_runtime.h>
#include <hip/hip_bf16.h>
#include <math.h>

typedef __hip_bfloat16 bf16;
typedef __attribute__((ext_vector_type(8))) short bf16x8v;
typedef __attribute__((ext_vector_type(4))) float f32x4v;

static constexpr int NB = 8, TT = 10, HH = 16, WW = 16, CC = 512;
static constexpr int NHEAD = 8, HIDN = 2048;
static constexpr int MTOK = NB * TT * HH * WW;          // 20480 tokens
static constexpr size_t MC = (size_t)MTOK * CC;         // 10485760
static constexpr float LNEPS = 1e-5f;
static constexpr float ATTSCALE = 0.125f;               // 1/sqrt(64)

static __device__ __forceinline__ float gelu_f(float x) {
    return 0.5f * x * (1.0f + erff(x * 0.70710678118654752f));
}

// ---------------- ws-too-small diagnostic ----------------
__global__ __launch_bounds__(256) void k_fill(float* __restrict__ out, float v, size_t n)
{
    size_t i = (size_t)blockIdx.x * 256 + threadIdx.x;
    if (i < n) out[i] = v;
}

// ---------------- fused LayerNorm (+permute, +pos); X fp32, dst bf16 ----------------
__global__ __launch_bounds__(64) void k_ln2(const float* __restrict__ X, bf16* __restrict__ dstA,
                                            bf16* __restrict__ dstB,
                                            const float* __restrict__ g, const float* __restrict__ b,
                                            const float* __restrict__ pos, int posoff, int mode)
{
    int m = blockIdx.x;
    int lane = threadIdx.x;
    const float* row = X + (size_t)m * CC;
    float v[8], s = 0.f, s2 = 0.f;
#pragma unroll
    for (int i = 0; i < 8; ++i) { v[i] = row[lane + i * 64]; s += v[i]; s2 += v[i] * v[i]; }
#pragma unroll
    for (int msk = 1; msk < 64; msk <<= 1) { s += __shfl_xor(s, msk); s2 += __shfl_xor(s2, msk); }
    float mean = s * (1.f / 512.f);
    float var  = fmaxf(s2 * (1.f / 512.f) - mean * mean, 0.f);
    float rr = rsqrtf(var + LNEPS);

    int r, pr = 0;
    if (mode == 0) { r = m; }
    else if (mode == 1) {
        int nt = m >> 8, hw = m & 255, h = hw >> 4, w = hw & 15;
        int l = (h & 7) * 8 + (w & 7);
        r = l * 320 + nt * 4 + (h >> 3) * 2 + (w >> 3);
        pr = l;
    } else if (mode == 3) {
        int n = m / 2560, rem = m - n * 2560;
        int t = rem >> 8;
        r = t * 2048 + n * 256 + (rem & 255);
        pr = t;
    } else {
        int n = m / 2560, rem = m - n * 2560;
        int t = rem >> 8, hw = rem & 255, h = hw >> 4, w = hw & 15;
        int ij = (h & 7) * 8 + (w & 7);
        r = (t * 64 + ij) * 32 + n * 4 + (h >> 3) * 2 + (w >> 3);
        pr = t * 64 + ij;
    }
#pragma unroll
    for (int i = 0; i < 8; ++i) {
        int c = lane + i * 64;
        float y = (v[i] - mean) * rr * g[c] + b[c];
        if (dstA) dstA[(size_t)r * CC + c] = __float2bfloat16(y);
        if (dstB) dstB[(size_t)r * CC + c] = __float2bfloat16(y + pos[(size_t)(posoff + pr) * CC + c]);
    }
}

// ---------------- gather-permute of fp32 `memory` into ts layout (+optional pos) ----------------
__global__ __launch_bounds__(256) void k_permmem(const float* __restrict__ in, bf16* __restrict__ out,
                                                 const float* __restrict__ pos, int posoff)
{
    size_t id = (size_t)blockIdx.x * 256 + threadIdx.x;
    if (id >= MC) return;
    int c = (int)(id & 511);
    int r = (int)(id >> 9);
    int b = r & 31, s = r >> 5;
    int t = s >> 6, ij = s & 63;
    int i = ij >> 3, j = ij & 7;
    int n = b >> 2, qh = (b >> 1) & 1, qw = b & 1;
    int m = (n * 10 + t) * 256 + (qh * 8 + i) * 16 + qw * 8 + j;
    float v = in[(size_t)m * CC + c];
    if (pos) v += pos[(size_t)(posoff + t * 64 + ij) * CC + c];
    out[id] = __float2bfloat16(v);
}

// ---------------- reverse permute + residual add into fp32 X ----------------
__global__ __launch_bounds__(256) void k_unperm_add(float* __restrict__ X, const bf16* __restrict__ Tb, int mode)
{
    size_t id = (size_t)blockIdx.x * 256 + threadIdx.x;
    if (id >= MC) return;
    int c = (int)(id & 511);
    int m = (int)(id >> 9);
    int r;
    if (mode == 1) {
        int nt = m >> 8, hw = m & 255;
        int h = hw >> 4, w = hw & 15;
        r = ((h & 7) * 8 + (w & 7)) * 320 + nt * 4 + (h >> 3) * 2 + (w >> 3);
    } else if (mode == 3) {
        int n = m / 2560, rem = m - n * 2560;
        r = (rem >> 8) * 2048 + n * 256 + (rem & 255);
    } else {
        int n = m / 2560, rem = m - n * 2560;
        int t = rem >> 8, hw = rem & 255;
        int h = hw >> 4, w = hw & 15;
        r = (t * 64 + (h & 7) * 8 + (w & 7)) * 32 + n * 4 + (h >> 3) * 2 + (w >> 3);
    }
    X[id] += (float)Tb[(size_t)r * CC + c];
}

__global__ __launch_bounds__(256) void k_add(float* __restrict__ X, const bf16* __restrict__ Y, size_t n)
{
    size_t i = (size_t)blockIdx.x * 256 + threadIdx.x;
    if (i < n) X[i] += (float)Y[i];
}

// ---------------- final residual add: FLOAT32 output ----------------
__global__ __launch_bounds__(256) void k_final(const float* __restrict__ X, const bf16* __restrict__ F,
                                               float* __restrict__ out, size_t n)
{
    size_t i = (size_t)blockIdx.x * 256 + threadIdx.x;
    if (i < n) out[i] = X[i] + (float)F[i];
}

// ---------------- MFMA GEMM: C = A(bf16, M x K) @ W(fp32, Nc x K)^T + bias; out bf16 ----------------
// 128x128 tile, BK=32, 4 waves each computing a 64x64 quadrant via 16 x mfma_f32_16x16x32_bf16.
// EPI 0: bias.  1: bias+BN+GELU.  3: bias+GELU.
template<int EPI>
__global__ __launch_bounds__(256) void k_mgemm(const bf16* __restrict__ A, const float* __restrict__ Wt,
                                               const float* __restrict__ bias, bf16* __restrict__ Cout,
                                               int Nc, int K,
                                               const float* __restrict__ bng, const float* __restrict__ bnb,
                                               const float* __restrict__ bnm, const float* __restrict__ bnv)
{
    __shared__ short As[128][40];   // [m][k], +8 pad
    __shared__ short Bs[128][40];   // [n][k], +8 pad
    int bm = blockIdx.y * 128, bn = blockIdx.x * 128;
    int tid = threadIdx.x;
    int lane = tid & 63, wave = tid >> 6;
    int wm = (wave & 1) * 64, wn = (wave >> 1) * 64;
    int fr = lane & 15;      // frag row (A) / col (B,D)
    int fq = lane >> 4;      // quad: k-offset fq*8 (A,B), row-offset fq*4 (D)

    f32x4v acc[4][4];
#pragma unroll
    for (int i = 0; i < 4; ++i)
#pragma unroll
        for (int j = 0; j < 4; ++j) acc[i][j] = (f32x4v){0.f, 0.f, 0.f, 0.f};

    for (int k0 = 0; k0 < K; k0 += 32) {
#pragma unroll
        for (int i = 0; i < 2; ++i) {
            int v = tid * 2 + i;                 // 0..511
            int m = v >> 2, kk = (v & 3) * 8;
            *(uint4*)&As[m][kk] = *(const uint4*)&A[(size_t)(bm + m) * K + k0 + kk];
            float4 w0 = *(const float4*)&Wt[(size_t)(bn + m) * K + k0 + kk];
            float4 w1 = *(const float4*)&Wt[(size_t)(bn + m) * K + k0 + kk + 4];
            union { bf16 h[8]; uint4 u; } t;
            t.h[0] = __float2bfloat16(w0.x); t.h[1] = __float2bfloat16(w0.y);
            t.h[2] = __float2bfloat16(w0.z); t.h[3] = __float2bfloat16(w0.w);
            t.h[4] = __float2bfloat16(w1.x); t.h[5] = __float2bfloat16(w1.y);
            t.h[6] = __float2bfloat16(w1.z); t.h[7] = __float2bfloat16(w1.w);
            *(uint4*)&Bs[m][kk] = t.u;
        }
        __syncthreads();
        bf16x8v af[4], bfr[4];
#pragma unroll
        for (int mi = 0; mi < 4; ++mi) af[mi]  = *(bf16x8v*)&As[wm + mi * 16 + fr][fq * 8];
#pragma unroll
        for (int ni = 0; ni < 4; ++ni) bfr[ni] = *(bf16x8v*)&Bs[wn + ni * 16 + fr][fq * 8];
#pragma unroll
        for (int mi = 0; mi < 4; ++mi)
#pragma unroll
            for (int ni = 0; ni < 4; ++ni)
                acc[mi][ni] = __builtin_amdgcn_mfma_f32_16x16x32_bf16(af[mi], bfr[ni], acc[mi][ni], 0, 0, 0);
        __syncthreads();
    }

#pragma unroll
    for (int mi = 0; mi < 4; ++mi)
#pragma unroll
        for (int ni = 0; ni < 4; ++ni)
#pragma unroll
            for (int r = 0; r < 4; ++r) {
                int m = bm + wm + mi * 16 + fq * 4 + r;
                int n = bn + wn + ni * 16 + fr;
                float v = acc[mi][ni][r] + bias[n];
                if constexpr (EPI == 1) {
                    v = (v - bnm[n]) * rsqrtf(bnv[n] + LNEPS) * bng[n] + bnb[n];
                    v = gelu_f(v);
                }
                if constexpr (EPI == 3) v = gelu_f(v);
                Cout[(size_t)m * Nc + n] = __float2bfloat16(v);
            }
}

// ---------------- elementwise dwconv3x3 + BN2 + GELU over a 4096-token chunk ----------------
__global__ __launch_bounds__(256) void k_dwc(const bf16* __restrict__ H1c, bf16* __restrict__ H2c,
                                             const float* __restrict__ dww, const float* __restrict__ dwb,
                                             const float* __restrict__ g2, const float* __restrict__ b2,
                                             const float* __restrict__ m2, const float* __restrict__ v2)
{
    size_t id = (size_t)blockIdx.x * 256 + threadIdx.x;
    if (id >= (size_t)4096 * HIDN) return;
    int k = (int)(id & 2047);
    int lm = (int)(id >> 11);
    int p = lm >> 8, hw = lm & 255, h = hw >> 4, w = hw & 15;
    float a = dwb[k];
#pragma unroll
    for (int dh = -1; dh <= 1; ++dh) {
        int h2 = h + dh;
        if (h2 < 0 || h2 > 15) continue;
#pragma unroll
        for (int dw = -1; dw <= 1; ++dw) {
            int w2 = w + dw;
            if (w2 < 0 || w2 > 15) continue;
            a += (float)H1c[(((size_t)p * 16 + h2) * 16 + w2) * HIDN + k]
               * dww[k * 9 + (dh + 1) * 3 + (dw + 1)];
        }
    }
    float xn = (a - m2[k]) * rsqrtf(v2[k] + LNEPS) * g2[k] + b2[k];
    H2c[id] = __float2bfloat16(gelu_f(xn));
}

// ---------------- generic MHA core: rows r = l*Bc + b, d=64, NH=8; bf16 I/O ----------------
__global__ __launch_bounds__(256) void k_attn(const bf16* __restrict__ Q, const bf16* __restrict__ K,
                                              const bf16* __restrict__ V, bf16* __restrict__ O,
                                              int L, int S, int Bc)
{
    __shared__ float sQ[16][68];
    __shared__ float sK[32][68];
    __shared__ float sV[32][68];
    __shared__ float sS[16][640];
    __shared__ float sRed[16][17];
    int b = blockIdx.x / NHEAD;
    int h = blockIdx.x - b * NHEAD;
    int ql0 = blockIdx.y * 16;
    int tid = threadIdx.x;
    int qi = tid >> 4, g = tid & 15;
    int SCv = (S + 31) & ~31;

    for (int t = tid; t < 16 * 64; t += 256) {
        int r = t >> 6, d = t & 63;
        int l = ql0 + r;
        sQ[r][d] = (l < L) ? (float)Q[((size_t)l * Bc + b) * CC + h * 64 + d] : 0.f;
    }
    __syncthreads();

    for (int s0 = 0; s0 < S; s0 += 32) {
        for (int t = tid; t < 32 * 64; t += 256) {
            int r = t >> 6, d = t & 63;
            int s = s0 + r;
            sK[r][d] = (s < S) ? (float)K[((size_t)s * Bc + b) * CC + h * 64 + d] : 0.f;
        }
        __syncthreads();
#pragma unroll
        for (int half = 0; half < 2; ++half) {
            int si = half * 16 + g;
            int s = s0 + si;
            float acc = 0.f;
#pragma unroll
            for (int d = 0; d < 64; ++d) acc += sQ[qi][d] * sK[si][d];
            sS[qi][s] = (s < S) ? acc * ATTSCALE : -60.f;
        }
        __syncthreads();
    }

    float pm = -60.f;
    for (int s = g; s < SCv; s += 16) pm = fmaxf(pm, sS[qi][s]);
    sRed[qi][g] = pm;
    __syncthreads();
    float mx = sRed[qi][0];
#pragma unroll
    for (int t = 1; t < 16; ++t) mx = fmaxf(mx, sRed[qi][t]);
    __syncthreads();
    float ps = 0.f;
    for (int s = g; s < SCv; s += 16) {
        float e = expf(sS[qi][s] - mx);
        sS[qi][s] = e;
        ps += e;
    }
    sRed[qi][g] = ps;
    __syncthreads();
    float sum = 0.f;
#pragma unroll
    for (int t = 0; t < 16; ++t) sum += sRed[qi][t];
    float inv = 1.f / fmaxf(sum, 1e-20f);

    float o0 = 0.f, o1 = 0.f, o2 = 0.f, o3 = 0.f;
    for (int s0 = 0; s0 < S; s0 += 32) {
        __syncthreads();
        for (int t = tid; t < 32 * 64; t += 256) {
            int r = t >> 6, d = t & 63;
            int s = s0 + r;
            sV[r][d] = (s < S) ? (float)V[((size_t)s * Bc + b) * CC + h * 64 + d] : 0.f;
        }
        __syncthreads();
#pragma unroll
        for (int si = 0; si < 32; ++si) {
            float w = sS[qi][s0 + si];
            o0 += w * sV[si][g * 4 + 0];
            o1 += w * sV[si][g * 4 + 1];
            o2 += w * sV[si][g * 4 + 2];
            o3 += w * sV[si][g * 4 + 3];
        }
    }
    int l = ql0 + qi;
    if (l < L) {
        bf16* op = O + ((size_t)l * Bc + b) * CC + h * 64 + g * 4;
        op[0] = __float2bfloat16(o0 * inv);
        op[1] = __float2bfloat16(o1 * inv);
        op[2] = __float2bfloat16(o2 * inv);
        op[3] = __float2bfloat16(o3 * inv);
    }
}

extern "C" void kernel_launch(void* const* d_in, const int* in_sizes, int n_in,
                              void* d_out, int out_size, void* d_ws, size_t ws_size,
                              hipStream_t stream)
{
    const float* query        = (const float*)d_in[0];
    const float* memory       = (const float*)d_in[1];
    const float* pos_local    = (const float*)d_in[2];
    const float* pos_temporal = (const float*)d_in[3];
    const float* pos_ts       = (const float*)d_in[4];
    const float* ln_g[5] = {(const float*)d_in[5], (const float*)d_in[7], (const float*)d_in[9], (const float*)d_in[11], (const float*)d_in[13]};
    const float* ln_b[5] = {(const float*)d_in[6], (const float*)d_in[8], (const float*)d_in[10], (const float*)d_in[12], (const float*)d_in[14]};
    const float* sa_w_in  = (const float*)d_in[15]; const float* sa_b_in  = (const float*)d_in[16];
    const float* sa_w_out = (const float*)d_in[17]; const float* sa_b_out = (const float*)d_in[18];
    const float* ta_w_in  = (const float*)d_in[19]; const float* ta_b_in  = (const float*)d_in[20];
    const float* ta_w_out = (const float*)d_in[21]; const float* ta_b_out = (const float*)d_in[22];
    const float* ca_w_in  = (const float*)d_in[23]; const float* ca_b_in  = (const float*)d_in[24];
    const float* ca_w_out = (const float*)d_in[25]; const float* ca_b_out = (const float*)d_in[26];
    const float* fc1_w = (const float*)d_in[27]; const float* fc1_b = (const float*)d_in[28];
    const float* dw_w  = (const float*)d_in[29]; const float* dw_b  = (const float*)d_in[30];
    const float* fc2_w = (const float*)d_in[31]; const float* fc2_b = (const float*)d_in[32];
    const float* bn1g = (const float*)d_in[33], *bn1b = (const float*)d_in[34], *bn1m = (const float*)d_in[35], *bn1v = (const float*)d_in[36];
    const float* bn2g = (const float*)d_in[37], *bn2b = (const float*)d_in[38], *bn2m = (const float*)d_in[39], *bn2v = (const float*)d_in[40];
    const float* bn3g = (const float*)d_in[41], *bn3b = (const float*)d_in[42], *bn3m = (const float*)d_in[43], *bn3v = (const float*)d_in[44];
    const float* lin1_w = (const float*)d_in[45]; const float* lin1_b = (const float*)d_in[46];
    const float* lin2_w = (const float*)d_in[47]; const float* lin2_b = (const float*)d_in[48];

    dim3 blk(256);
    int gMC = (int)(MC / 256);

    size_t need = MC * 4 + 4 * MC * 2;
    if (ws_size < need) {
        k_fill<<<gMC, blk, 0, stream>>>((float*)d_out, 700.f, MC);
        return;
    }
    float* X = (float*)d_ws;
    bf16* B0 = (bf16*)((char*)d_ws + MC * 4);
    bf16* B1 = B0 + MC;
    bf16* B2 = B1 + MC;
    bf16* B3 = B2 + MC;
    const float* nulf = nullptr;
    bf16* nulm = nullptr;

    hipMemcpyAsync(X, query, MC * sizeof(float), hipMemcpyDeviceToDevice, stream);

    // ---- stage 1: spatial window MHSA ----
    k_ln2<<<MTOK, 64, 0, stream>>>(X, B0, B1, ln_g[0], ln_b[0], pos_local, 0, 1);
    k_mgemm<0><<<dim3(4, 160), blk, 0, stream>>>(B1, sa_w_in, sa_b_in, B2, 512, 512, nulf, nulf, nulf, nulf);
    k_mgemm<0><<<dim3(4, 160), blk, 0, stream>>>(B1, sa_w_in + 512 * 512, sa_b_in + 512, B3, 512, 512, nulf, nulf, nulf, nulf);
    k_mgemm<0><<<dim3(4, 160), blk, 0, stream>>>(B0, sa_w_in + 2 * 512 * 512, sa_b_in + 1024, B1, 512, 512, nulf, nulf, nulf, nulf);
    k_attn<<<dim3(320 * NHEAD, 4), blk, 0, stream>>>(B2, B3, B1, B0, 64, 64, 320);
    k_mgemm<0><<<dim3(4, 160), blk, 0, stream>>>(B0, sa_w_out, sa_b_out, B2, 512, 512, nulf, nulf, nulf, nulf);
    k_unperm_add<<<gMC, blk, 0, stream>>>(X, B2, 1);

    // ---- stage 2: MlpDWBN, chunked over 16-plane slabs ----
    k_ln2<<<MTOK, 64, 0, stream>>>(X, B0, nulm, ln_g[1], ln_b[1], nulf, 0, 0);
    for (int c = 0; c < 5; ++c) {
        int off = c * 4096;
        k_mgemm<1><<<dim3(16, 32), blk, 0, stream>>>(B0 + (size_t)off * CC, fc1_w, fc1_b, B1, 2048, 512,
                                                     bn1g, bn1b, bn1m, bn1v);
        k_dwc<<<32768, blk, 0, stream>>>(B1, B3, dw_w, dw_b, bn2g, bn2b, bn2m, bn2v);
        k_mgemm<1><<<dim3(4, 32), blk, 0, stream>>>(B3, fc2_w, fc2_b, B2 + (size_t)off * CC, 512, 2048,
                                                    bn3g, bn3b, bn3m, bn3v);
    }
    k_add<<<gMC, blk, 0, stream>>>(X, B2, MC);

    // ---- stage 3: temporal MHSA ----
    k_ln2<<<MTOK, 64, 0, stream>>>(X, B0, B1, ln_g[2], ln_b[2], pos_temporal, 0, 3);
    k_mgemm<0><<<dim3(4, 160), blk, 0, stream>>>(B1, ta_w_in, ta_b_in, B2, 512, 512, nulf, nulf, nulf, nulf);
    k_mgemm<0><<<dim3(4, 160), blk, 0, stream>>>(B1, ta_w_in + 512 * 512, ta_b_in + 512, B3, 512, 512, nulf, nulf, nulf, nulf);
    k_mgemm<0><<<dim3(4, 160), blk, 0, stream>>>(B0, ta_w_in + 2 * 512 * 512, ta_b_in + 1024, B1, 512, 512, nulf, nulf, nulf, nulf);
    k_attn<<<dim3(2048 * NHEAD, 1), blk, 0, stream>>>(B2, B3, B1, B0, 10, 10, 2048);
    k_mgemm<0><<<dim3(4, 160), blk, 0, stream>>>(B0, ta_w_out, ta_b_out, B2, 512, 512, nulf, nulf, nulf, nulf);
    k_unperm_add<<<gMC, blk, 0, stream>>>(X, B2, 3);

    // ---- stage 4: temporal-spatial cross-attention ----
    k_ln2<<<MTOK, 64, 0, stream>>>(X, nulm, B1, ln_g[3], ln_b[3], pos_ts, 640, 4);
    k_mgemm<0><<<dim3(4, 160), blk, 0, stream>>>(B1, ca_w_in, ca_b_in, B2, 512, 512, nulf, nulf, nulf, nulf);
    k_permmem<<<gMC, blk, 0, stream>>>(memory, B1, pos_ts, 0);
    k_mgemm<0><<<dim3(4, 160), blk, 0, stream>>>(B1, ca_w_in + 512 * 512, ca_b_in + 512, B3, 512, 512, nulf, nulf, nulf, nulf);
    k_permmem<<<gMC, blk, 0, stream>>>(memory, B1, nulf, 0);
    k_mgemm<0><<<dim3(4, 160), blk, 0, stream>>>(B1, ca_w_in + 2 * 512 * 512, ca_b_in + 1024, B0, 512, 512, nulf, nulf, nulf, nulf);
    k_attn<<<dim3(32 * NHEAD, 40), blk, 0, stream>>>(B2, B3, B0, B1, 640, 640, 32);
    k_mgemm<0><<<dim3(4, 160), blk, 0, stream>>>(B1, ca_w_out, ca_b_out, B2, 512, 512, nulf, nulf, nulf, nulf);
    k_unperm_add<<<gMC, blk, 0, stream>>>(X, B2, 4);

    // ---- stage 5: final FFN, chunked ----
    k_ln2<<<MTOK, 64, 0, stream>>>(X, B0, nulm, ln_g[4], ln_b[4], nulf, 0, 0);
    for (int c = 0; c < 5; ++c) {
        int off = c * 4096;
        k_mgemm<3><<<dim3(16, 32), blk, 0, stream>>>(B0 + (size_t)off * CC, lin1_w, lin1_b, B1, 2048, 512,
                                                     nulf, nulf, nulf, nulf);
        k_mgemm<0><<<dim3(4, 32), blk, 0, stream>>>(B1, lin2_w, lin2_b, B2 + (size_t)off * CC, 512, 2048,
                                                    nulf, nulf, nulf, nulf);
    }
    k_final<<<gMC, blk, 0, stream>>>(X, B2, (float*)d_out, MC);
}